// Round 1
// baseline (18644.101 us; speedup 1.0000x reference)
//
#include <hip/hip_runtime.h>
#include <stdint.h>

#define Hdim 512
#define Bsz 64
#define Tlen 1024
#define RING 8

typedef __attribute__((ext_vector_type(8))) short short8;
typedef __attribute__((ext_vector_type(4))) float f32x4;

__device__ __forceinline__ short f2bf(float f) {
  uint32_t u = __float_as_uint(f);
  u += 0x7fffu + ((u >> 16) & 1u);   // RNE
  return (short)(u >> 16);
}

__device__ __forceinline__ f32x4 mfma16(short8 a, short8 b, f32x4 c) {
  return __builtin_amdgcn_mfma_f32_16x16x32_bf16(a, b, c, 0, 0, 0);
}

__device__ __forceinline__ void wait_ge(const uint32_t* p, uint32_t v) {
  uint32_t it = 0;
  while (__hip_atomic_load(p, __ATOMIC_RELAXED, __HIP_MEMORY_SCOPE_AGENT) < v) {
    __builtin_amdgcn_s_sleep(1);
    if (++it > (1u << 24)) break;  // failsafe against hang
  }
}

__global__ void out_init(float* out, const float* bout) {
  int i = blockIdx.x * 256 + threadIdx.x;
  if (i < Bsz * Tlen) out[i] = bout[0];
}

// Pack weights into MFMA B-fragment order, bf16.
// Chunk layout: [L0: wg(64) x ks(16) x nt(2) x lane(64)][L1: wg x 32 x 2 x 64][L2: ...]
// Each chunk = 8 bf16 (16B). Fragment: lane l holds B[k][n], n = nt*16+(l&15),
// k = ks*32 + (l>>4)*8 + e.  n (col) -> gate = n>>3, dim = wg*8 + (n&7),
// row = gate*512 + dim.  k<512 -> Wih[row][k] (layers 1,2), k>=512 -> Whh[row][k-512].
// Layer 0: K=512, all Whh0.
__global__ void pack_kernel(const float* __restrict__ Whh0,
                            const float* __restrict__ Wih1, const float* __restrict__ Whh1,
                            const float* __restrict__ Wih2, const float* __restrict__ Whh2,
                            short* __restrict__ Bpack) {
  int ch = blockIdx.x * 256 + threadIdx.x;
  const int L0C = 64 * 16 * 2 * 64;       // 131072
  const int L12C = 64 * 32 * 2 * 64;      // 262144
  if (ch >= L0C + 2 * L12C) return;
  int layer, rel, KS;
  const float* Wih;
  const float* Whh;
  if (ch < L0C) { layer = 0; rel = ch; KS = 16; Wih = nullptr; Whh = Whh0; }
  else if (ch < L0C + L12C) { layer = 1; rel = ch - L0C; KS = 32; Wih = Wih1; Whh = Whh1; }
  else { layer = 2; rel = ch - L0C - L12C; KS = 32; Wih = Wih2; Whh = Whh2; }
  int lane = rel & 63;
  int nt = (rel >> 6) & 1;
  int rest = rel >> 7;          // wg*KS + ks
  int ks = rest % KS;
  int wg = rest / KS;
  int col = nt * 16 + (lane & 15);
  int row = (col >> 3) * Hdim + wg * 8 + (col & 7);
  int kbase = ks * 32 + (lane >> 4) * 8;
  short8 v;
#pragma unroll
  for (int e = 0; e < 8; ++e) {
    int k = kbase + e;
    float w;
    if (layer == 0) w = Whh[row * Hdim + k];
    else w = (k < Hdim) ? Wih[row * Hdim + k] : Whh[row * Hdim + (k - Hdim)];
    v[e] = f2bf(w);
  }
  ((short8*)Bpack)[ch] = v;
}

__global__ __launch_bounds__(256, 1)
void lstm_persist(const float* __restrict__ x,
                  const float* __restrict__ Wih0v,
                  const float* __restrict__ bih0, const float* __restrict__ bhh0,
                  const float* __restrict__ bih1, const float* __restrict__ bhh1,
                  const float* __restrict__ bih2, const float* __restrict__ bhh2,
                  const float* __restrict__ Wout,
                  const short* __restrict__ Bpack,
                  short* __restrict__ rings,
                  uint32_t* __restrict__ cnt,
                  float* __restrict__ out) {
  const int blk = blockIdx.x;
  const int layer = blk >> 6;     // 0..2
  const int wg = blk & 63;
  const int tid = threadIdx.x;
  const int lane = tid & 63;
  const int wave = tid >> 6;      // 0..3
  const int bm = wave * 16;       // batch tile base

  // ---- persistent B fragments in registers ----
  short8 bw[32][2];
  {
    const short8* bp = (const short8*)Bpack;
    const int base = (layer == 0) ? 0 : (layer == 1 ? 131072 : 131072 + 262144);
    if (layer == 0) {
#pragma unroll
      for (int ks = 0; ks < 16; ++ks) {
        bw[ks][0] = bp[base + ((wg * 16 + ks) * 2 + 0) * 64 + lane];
        bw[ks][1] = bp[base + ((wg * 16 + ks) * 2 + 1) * 64 + lane];
      }
    } else {
#pragma unroll
      for (int ks = 0; ks < 32; ++ks) {
        bw[ks][0] = bp[base + ((wg * 32 + ks) * 2 + 0) * 64 + lane];
        bw[ks][1] = bp[base + ((wg * 32 + ks) * 2 + 1) * 64 + lane];
      }
    }
  }

  // ---- per-lane constants ----
  const float* bih = (layer == 0) ? bih0 : (layer == 1 ? bih1 : bih2);
  const float* bhh = (layer == 0) ? bhh0 : (layer == 1 ? bhh1 : bhh2);
  const int col0 = (lane & 15);
  const int col1 = 16 + (lane & 15);
  const int row0 = (col0 >> 3) * Hdim + wg * 8 + (col0 & 7);
  const int row1 = (col1 >> 3) * Hdim + wg * 8 + (col1 & 7);
  const float bias0 = bih[row0] + bhh[row0];
  const float bias1 = bih[row1] + bhh[row1];
  float xw0 = 0.f, xw1 = 0.f, woutd = 0.f;
  if (layer == 0) { xw0 = Wih0v[row0]; xw1 = Wih0v[row1]; }
  if (layer == 2) woutd = Wout[wg * 8 + (lane & 7)];

  short* ringL = rings + layer * (RING * Bsz * Hdim);
  const short* ringP = (layer > 0) ? rings + (layer - 1) * (RING * Bsz * Hdim) : nullptr;
  uint32_t* cntL = cnt + layer * Tlen;
  const uint32_t* cntP = (layer > 0) ? cnt + (layer - 1) * Tlen : nullptr;
  const uint32_t* cntN = (layer < 2) ? cnt + (layer + 1) * Tlen : nullptr;

  const int aoff = (bm + (lane & 15)) * Hdim + (lane >> 4) * 8;  // A-frag element offset in a slot
  const int bX = bm + 4 * (lane >> 4);                           // acc-row batch base

  float c[4] = {0.f, 0.f, 0.f, 0.f};

  for (int t = 0; t < Tlen; ++t) {
    // ---- phase 1: cross-layer input (has pipeline slack) ----
    if (tid == 0 && layer > 0) wait_ge(cntP + t, 64);
    __syncthreads();
    __builtin_amdgcn_fence(__ATOMIC_ACQUIRE, "agent");

    f32x4 acc0 = {bias0, bias0, bias0, bias0};
    f32x4 acc1 = {bias1, bias1, bias1, bias1};

    if (layer > 0) {
      const short* xin = ringP + (t & (RING - 1)) * (Bsz * Hdim);
#pragma unroll
      for (int ks = 0; ks < 16; ++ks) {
        short8 a = *(const short8*)(xin + aoff + ks * 32);
        acc0 = mfma16(a, bw[ks][0], acc0);
        acc1 = mfma16(a, bw[ks][1], acc1);
      }
    } else if (t > 0) {
#pragma unroll
      for (int r = 0; r < 4; ++r) {
        float xv = x[(bX + r) * Tlen + (t - 1)];  // DELAY=1
        acc0[r] += xw0 * xv;
        acc1[r] += xw1 * xv;
      }
    }

    // ---- phase 2: own-layer recurrence (critical path) ----
    if (tid == 0) {
      if (t > 0) wait_ge(cntL + (t - 1), 64);
      if (layer < 2 && t >= RING) wait_ge(cntN + (t - RING), 64);  // ring backpressure
    }
    __syncthreads();
    __builtin_amdgcn_fence(__ATOMIC_ACQUIRE, "agent");

    if (t > 0) {
      const short* hin = ringL + ((t - 1) & (RING - 1)) * (Bsz * Hdim);
      const int kb = (layer == 0) ? 0 : 16;
#pragma unroll
      for (int ks = 0; ks < 16; ++ks) {
        short8 a = *(const short8*)(hin + aoff + ks * 32);
        acc0 = mfma16(a, bw[kb + ks][0], acc0);
        acc1 = mfma16(a, bw[kb + ks][1], acc1);
      }
    }

    // ---- activations & state update ----
    // acc0: cols 0-15  -> gate i (lanes with (lane&8)==0) / gate f ((lane&8)==1), dim = lane&7
    // acc1: cols 16-31 -> gate g / gate o
    short* hout = ringL + (t & (RING - 1)) * (Bsz * Hdim);
    float parts[4];
#pragma unroll
    for (int r = 0; r < 4; ++r) {
      float a0 = acc0[r], a1 = acc1[r];
      float p0 = __shfl_xor(a0, 8);   // partner's gate (f on low lanes)
      float p1 = __shfl_xor(a1, 8);   // partner's gate (o on low lanes)
      float iv = 1.f / (1.f + __expf(-a0));
      float fv = 1.f / (1.f + __expf(-p0));
      float gv = tanhf(a1);
      float ov = 1.f / (1.f + __expf(-p1));
      c[r] = fv * c[r] + iv * gv;
      float hv = ov * tanhf(c[r]);
      if ((lane & 8) == 0) hout[(bX + r) * Hdim + wg * 8 + (lane & 7)] = f2bf(hv);
      parts[r] = hv * woutd;
    }
    if (layer == 2) {
#pragma unroll
      for (int r = 0; r < 4; ++r) {
        parts[r] += __shfl_xor(parts[r], 1);
        parts[r] += __shfl_xor(parts[r], 2);
        parts[r] += __shfl_xor(parts[r], 4);
        if ((lane & 15) == 0) atomicAdd(out + (bX + r) * Tlen + t, parts[r]);
      }
    }

    // ---- release: publish h slice ----
    __syncthreads();
    if (tid == 0) {
      __builtin_amdgcn_fence(__ATOMIC_RELEASE, "agent");
      atomicAdd(cntL + t, 1u);
    }
  }
}

extern "C" void kernel_launch(void* const* d_in, const int* in_sizes, int n_in,
                              void* d_out, int out_size, void* d_ws, size_t ws_size,
                              hipStream_t stream) {
  const float* x    = (const float*)d_in[0];
  const float* Wih0 = (const float*)d_in[1];
  const float* Whh0 = (const float*)d_in[2];
  const float* bih0 = (const float*)d_in[3];
  const float* bhh0 = (const float*)d_in[4];
  const float* Wih1 = (const float*)d_in[5];
  const float* Whh1 = (const float*)d_in[6];
  const float* bih1 = (const float*)d_in[7];
  const float* bhh1 = (const float*)d_in[8];
  const float* Wih2 = (const float*)d_in[9];
  const float* Whh2 = (const float*)d_in[10];
  const float* bih2 = (const float*)d_in[11];
  const float* bhh2 = (const float*)d_in[12];
  const float* Wout = (const float*)d_in[13];
  const float* bout = (const float*)d_in[14];

  char* ws = (char*)d_ws;
  short* Bpack = (short*)ws;                            // 10,485,760 B
  short* rings = (short*)(ws + 10485760);               // 3*8*64*512*2 = 1,572,864 B
  uint32_t* cnt = (uint32_t*)(ws + 10485760 + 1572864); // 3*1024*4 = 12,288 B
  float* out = (float*)d_out;

  hipMemsetAsync(cnt, 0, 3 * Tlen * sizeof(uint32_t), stream);
  out_init<<<(Bsz * Tlen + 255) / 256, 256, 0, stream>>>(out, bout);
  pack_kernel<<<(655360 + 255) / 256, 256, 0, stream>>>(Whh0, Wih1, Whh1, Wih2, Whh2, Bpack);
  lstm_persist<<<192, 256, 0, stream>>>(x, Wih0, bih0, bhh0, bih1, bhh1, bih2, bhh2,
                                        Wout, Bpack, rings, cnt, out);
}